// Round 5
// baseline (6077.905 us; speedup 1.0000x reference)
//
#include <hip/hip_runtime.h>
#include <stdint.h>

typedef unsigned short u16;

#define NTOK 32768
#define FDIM 512

__device__ __forceinline__ float bflo(uint32_t p){ union{uint32_t u; float f;} v; v.u = p<<16; return v.f; }
__device__ __forceinline__ float bfhi(uint32_t p){ union{uint32_t u; float f;} v; v.u = p & 0xffff0000u; return v.f; }
__device__ __forceinline__ float bf1(u16 x){ union{uint32_t u; float f;} v; v.u = ((uint32_t)x)<<16; return v.f; }
__device__ __forceinline__ u16 f2bf(float f){
  union{float f; uint32_t u;} v; v.f = f;
  uint32_t u = v.u;
  u += 0x7fffu + ((u>>16)&1u);   // round-to-nearest-even
  return (u16)(u>>16);
}

// -------------------- embedding + positional encoding --------------------
__global__ __launch_bounds__(256) void embed_kernel(const int* __restrict__ text,
    const float* __restrict__ emb, const float* __restrict__ pe,
    float* __restrict__ xf, u16* __restrict__ xb, const int tok0){
  const int gid = blockIdx.x*256 + threadIdx.x;
  const int base = gid*4;
  const int tl = base >> 9;
  const int f  = base & 511;
  const int tg = tl + tok0;
  const int s  = tg & 511;
  const int tok = text[tg];
  const float4 e4 = *(const float4*)(emb + (size_t)tok*FDIM + f);
  const float4 p4 = *(const float4*)(pe  + (size_t)s*FDIM + f);
  const float o0 = e4.x + p4.x;
  const float o1 = e4.y + p4.y;
  const float o2 = e4.z + p4.z;
  const float o3 = e4.w + p4.w;
  float4 of; of.x=o0; of.y=o1; of.z=o2; of.w=o3;
  *(float4*)(xf + base) = of;
  ushort4 ob; ob.x=f2bf(o0); ob.y=f2bf(o1); ob.z=f2bf(o2); ob.w=f2bf(o3);
  *(ushort4*)(xb + base) = ob;
}

// -------------------- simple VALU fp32 GEMM (trusted path) --------------------
// C[M x ldC] = A[M x 512] * W[512 x N] + bias (+resid). W in ORIGINAL layout (n contiguous).
// MODE 0: A fp32 (xf), W/bias selected from {W0,b0|W1,b1|W2,b2} per 512-col range.
// MODE 1: A bf16 (y1b), W0/b0 only, + bf16 resid.
template<int MODE>
__global__ __launch_bounds__(256) void gemm_valu(
    const void* __restrict__ Av,
    const float* __restrict__ W0, const float* __restrict__ W1, const float* __restrict__ W2,
    const float* __restrict__ b0, const float* __restrict__ b1, const float* __restrict__ b2,
    const u16* __restrict__ resid, u16* __restrict__ C, int ldC){
  __shared__ float Asf[64][33];
  __shared__ float Bsf[32][68];            // stride 68 floats: 16B-aligned rows
  const int tid = threadIdx.x;
  const int m0  = blockIdx.x*64;
  const int n0g = blockIdx.y*64;
  const float* Wsel; const float* bsel; int col0;
  if (MODE==0){
    if      (n0g <  512){ Wsel=W0; bsel=b0; col0=n0g;      }
    else if (n0g < 1024){ Wsel=W1; bsel=b1; col0=n0g-512;  }
    else                { Wsel=W2; bsel=b2; col0=n0g-1024; }
  } else {                Wsel=W0; bsel=b0; col0=n0g;      }
  const int ty = tid>>4, tx = tid&15;      // 16x16 threads, 4x4 outputs each
  float acc[4][4];
  #pragma unroll
  for (int i=0;i<4;i++)
    #pragma unroll
    for (int j=0;j<4;j++) acc[i][j] = 0.f;

  const int arow = tid>>2, asub = tid&3;   // A-tile: 64 rows x 32 k, 8 elems/thread
  const int krow = tid>>3, cofs = (tid&7)*8; // B-tile: 32 k x 64 cols, 8 floats/thread

  for (int kb=0; kb<512; kb+=32){
    __syncthreads();
    if (MODE==0){
      const float* A = (const float*)Av;
      const float4 a0 = *(const float4*)(A + (size_t)(m0+arow)*FDIM + kb + asub*8);
      const float4 a1 = *(const float4*)(A + (size_t)(m0+arow)*FDIM + kb + asub*8 + 4);
      Asf[arow][asub*8+0]=a0.x; Asf[arow][asub*8+1]=a0.y;
      Asf[arow][asub*8+2]=a0.z; Asf[arow][asub*8+3]=a0.w;
      Asf[arow][asub*8+4]=a1.x; Asf[arow][asub*8+5]=a1.y;
      Asf[arow][asub*8+6]=a1.z; Asf[arow][asub*8+7]=a1.w;
    } else {
      const u16* A = (const u16*)Av;
      const int4 av = *(const int4*)(A + (size_t)(m0+arow)*FDIM + kb + asub*8);
      const uint32_t* ap = (const uint32_t*)&av;
      #pragma unroll
      for (int p=0;p<4;p++){
        Asf[arow][asub*8+2*p]   = bflo(ap[p]);
        Asf[arow][asub*8+2*p+1] = bfhi(ap[p]);
      }
    }
    {
      const float4 w0 = *(const float4*)(Wsel + (size_t)(kb+krow)*FDIM + col0 + cofs);
      const float4 w1 = *(const float4*)(Wsel + (size_t)(kb+krow)*FDIM + col0 + cofs + 4);
      Bsf[krow][cofs+0]=w0.x; Bsf[krow][cofs+1]=w0.y;
      Bsf[krow][cofs+2]=w0.z; Bsf[krow][cofs+3]=w0.w;
      Bsf[krow][cofs+4]=w1.x; Bsf[krow][cofs+5]=w1.y;
      Bsf[krow][cofs+6]=w1.z; Bsf[krow][cofs+7]=w1.w;
    }
    __syncthreads();
    #pragma unroll
    for (int kk=0; kk<32; kk++){
      const float a0 = Asf[ty*4+0][kk];
      const float a1 = Asf[ty*4+1][kk];
      const float a2 = Asf[ty*4+2][kk];
      const float a3 = Asf[ty*4+3][kk];
      const float4 bv = *(const float4*)(&Bsf[kk][tx*4]);
      acc[0][0] += a0*bv.x; acc[0][1] += a0*bv.y; acc[0][2] += a0*bv.z; acc[0][3] += a0*bv.w;
      acc[1][0] += a1*bv.x; acc[1][1] += a1*bv.y; acc[1][2] += a1*bv.z; acc[1][3] += a1*bv.w;
      acc[2][0] += a2*bv.x; acc[2][1] += a2*bv.y; acc[2][2] += a2*bv.z; acc[2][3] += a2*bv.w;
      acc[3][0] += a3*bv.x; acc[3][1] += a3*bv.y; acc[3][2] += a3*bv.z; acc[3][3] += a3*bv.w;
    }
  }

  #pragma unroll
  for (int rr=0; rr<4; rr++){
    const size_t row = (size_t)(m0 + ty*4 + rr);
    #pragma unroll
    for (int cc=0; cc<4; cc++){
      const int lc = tx*4 + cc;
      const int gc = n0g + lc;
      float v = acc[rr][cc] + bsel[col0 + lc];
      if (MODE==1) v += bf1(resid[row*FDIM + gc]);
      C[row*(size_t)ldC + gc] = f2bf(v);
    }
  }
}

// -------------------- per-token head-attention + residual + LN1 (1 wave = 1 token) --------------------
__global__ __launch_bounds__(256) void attn_ln1(const u16* __restrict__ qkvb,
    const float* __restrict__ xf, const float* __restrict__ gam, const float* __restrict__ bet,
    u16* __restrict__ y1b){
  __shared__ __attribute__((aligned(16))) u16 sQ[4][1536];
  __shared__ float sWt[4][64];
  const int tid = threadIdx.x, w = tid>>6, l = tid&63;
  const int t = blockIdx.x*4 + w;
  {
    const int4* src = (const int4*)(qkvb + (size_t)t*1536);
    int4* dst = (int4*)(&sQ[w][0]);
    #pragma unroll
    for (int i=0;i<3;i++) dst[i*64 + l] = src[i*64 + l];
  }
  __syncthreads();
  const int h = l>>3, g = l&7;
  const u16* qrow = &sQ[w][h*64];
  const u16* krow = &sQ[w][512 + g*64];
  float sc = 0.f;
  const int dstart = (l&31)*2;
  #pragma unroll
  for (int i=0;i<32;i++){
    const int d = (dstart + 2*i) & 63;
    const uint32_t qp = *(const uint32_t*)(qrow + d);
    const uint32_t kp = *(const uint32_t*)(krow + d);
    sc += bflo(qp)*bflo(kp) + bfhi(qp)*bfhi(kp);
  }
  float mx = sc;
  mx = fmaxf(mx, __shfl_xor(mx,1));
  mx = fmaxf(mx, __shfl_xor(mx,2));
  mx = fmaxf(mx, __shfl_xor(mx,4));
  const float e = __expf(sc - mx);
  float ssum = e;
  ssum += __shfl_xor(ssum,1);
  ssum += __shfl_xor(ssum,2);
  ssum += __shfl_xor(ssum,4);
  sWt[w][l] = e / ssum;
  __syncthreads();
  float wt[8];
  #pragma unroll
  for (int gg=0;gg<8;gg++) wt[gg] = sWt[w][h*8+gg];
  float att[8] = {0,0,0,0,0,0,0,0};
  const int d0 = (l&7)*8;
  #pragma unroll
  for (int gg=0;gg<8;gg++){
    const int4 vv = *(const int4*)(&sQ[w][1024 + gg*64 + d0]);
    const uint32_t* vp = (const uint32_t*)&vv;
    #pragma unroll
    for (int p=0;p<4;p++){
      att[2*p]   += wt[gg]*bflo(vp[p]);
      att[2*p+1] += wt[gg]*bfhi(vp[p]);
    }
  }
  const size_t rb = (size_t)t*FDIM + l*8;
  float y[8]; float s1=0.f, s2=0.f;
  const float4 x0 = *(const float4*)(xf + rb);
  const float4 x1 = *(const float4*)(xf + rb + 4);
  y[0]=att[0]+x0.x; y[1]=att[1]+x0.y; y[2]=att[2]+x0.z; y[3]=att[3]+x0.w;
  y[4]=att[4]+x1.x; y[5]=att[5]+x1.y; y[6]=att[6]+x1.z; y[7]=att[7]+x1.w;
  #pragma unroll
  for (int j=0;j<8;j++){ s1 += y[j]; s2 += y[j]*y[j]; }
  #pragma unroll
  for (int off=1; off<64; off<<=1){ s1 += __shfl_xor(s1,off); s2 += __shfl_xor(s2,off); }
  const float mean = s1*(1.f/512.f);
  const float var  = s2*(1.f/512.f) - mean*mean;
  const float rstd = rsqrtf(var + 1e-5f);
  const float4 g0 = *(const float4*)(gam + l*8);
  const float4 g1v = *(const float4*)(gam + l*8 + 4);
  const float4 b0v = *(const float4*)(bet + l*8);
  const float4 b1v = *(const float4*)(bet + l*8 + 4);
  float of[8];
  of[0]=(y[0]-mean)*rstd*g0.x + b0v.x;
  of[1]=(y[1]-mean)*rstd*g0.y + b0v.y;
  of[2]=(y[2]-mean)*rstd*g0.z + b0v.z;
  of[3]=(y[3]-mean)*rstd*g0.w + b0v.w;
  of[4]=(y[4]-mean)*rstd*g1v.x + b1v.x;
  of[5]=(y[5]-mean)*rstd*g1v.y + b1v.y;
  of[6]=(y[6]-mean)*rstd*g1v.z + b1v.z;
  of[7]=(y[7]-mean)*rstd*g1v.w + b1v.w;
  u16 ob[8] __attribute__((aligned(16)));
  #pragma unroll
  for (int j=0;j<8;j++) ob[j] = f2bf(of[j]);
  *(int4*)(y1b + rb) = *(const int4*)ob;
}

// -------------------- LN2 over z; final layer writes FP32 output --------------------
__global__ __launch_bounds__(256) void ln2_kernel(const u16* __restrict__ z,
    const float* __restrict__ gam, const float* __restrict__ bet,
    float* __restrict__ xf, u16* __restrict__ xb, float* __restrict__ outp, const int final_){
  const int tid = threadIdx.x, w = tid>>6, l = tid&63;
  const int t = blockIdx.x*4 + w;
  const size_t rb = (size_t)t*FDIM + l*8;
  const int4 zv = *(const int4*)(z + rb);
  const uint32_t* zp = (const uint32_t*)&zv;
  float y[8];
  #pragma unroll
  for (int p=0;p<4;p++){ y[2*p]=bflo(zp[p]); y[2*p+1]=bfhi(zp[p]); }
  float s1=0.f, s2=0.f;
  #pragma unroll
  for (int j=0;j<8;j++){ s1+=y[j]; s2+=y[j]*y[j]; }
  #pragma unroll
  for (int off=1; off<64; off<<=1){ s1 += __shfl_xor(s1,off); s2 += __shfl_xor(s2,off); }
  const float mean = s1*(1.f/512.f);
  const float var  = s2*(1.f/512.f) - mean*mean;
  const float rstd = rsqrtf(var + 1e-5f);
  const float4 g0 = *(const float4*)(gam + l*8);
  const float4 g1v = *(const float4*)(gam + l*8 + 4);
  const float4 b0v = *(const float4*)(bet + l*8);
  const float4 b1v = *(const float4*)(bet + l*8 + 4);
  float of[8];
  of[0]=(y[0]-mean)*rstd*g0.x + b0v.x;
  of[1]=(y[1]-mean)*rstd*g0.y + b0v.y;
  of[2]=(y[2]-mean)*rstd*g0.z + b0v.z;
  of[3]=(y[3]-mean)*rstd*g0.w + b0v.w;
  of[4]=(y[4]-mean)*rstd*g1v.x + b1v.x;
  of[5]=(y[5]-mean)*rstd*g1v.y + b1v.y;
  of[6]=(y[6]-mean)*rstd*g1v.z + b1v.z;
  of[7]=(y[7]-mean)*rstd*g1v.w + b1v.w;
  float4 o0; o0.x=of[0]; o0.y=of[1]; o0.z=of[2]; o0.w=of[3];
  float4 o1; o1.x=of[4]; o1.y=of[5]; o1.z=of[6]; o1.w=of[7];
  if (final_){
    *(float4*)(outp + rb) = o0;              // FP32 output per harness contract
    *(float4*)(outp + rb + 4) = o1;
  } else {
    *(float4*)(xf + rb) = o0;
    *(float4*)(xf + rb + 4) = o1;
    u16 ob[8] __attribute__((aligned(16)));
    #pragma unroll
    for (int j=0;j<8;j++) ob[j] = f2bf(of[j]);
    *(int4*)(xb + rb) = *(const int4*)ob;
  }
}

extern "C" void kernel_launch(void* const* d_in, const int* in_sizes, int n_in,
                              void* d_out, int out_size, void* d_ws, size_t ws_size,
                              hipStream_t stream){
  const int*   text = (const int*)d_in[0];
  const float* emb = (const float*)d_in[1];
  const float* pe  = (const float*)d_in[2];
  const float* Wq  = (const float*)d_in[3];
  const float* bq  = (const float*)d_in[4];
  const float* Wk  = (const float*)d_in[5];
  const float* bk  = (const float*)d_in[6];
  const float* Wv  = (const float*)d_in[7];
  const float* bv  = (const float*)d_in[8];
  const float* g1  = (const float*)d_in[9];
  const float* be1 = (const float*)d_in[10];
  const float* Wf  = (const float*)d_in[11];
  const float* bf_ = (const float*)d_in[12];
  const float* g2  = (const float*)d_in[13];
  const float* be2 = (const float*)d_in[14];
  float* outp = (float*)d_out;               // reference output dtype = float32

  // ---- layout: per-token xf 2048 + xb 1024 + y1b 1024 + qkv 3072 = 7168 B
  int T = 16384;
  while (T > 2048 && (size_t)T*7168 > ws_size) T >>= 1;

  char* act = (char*)d_ws;
  float* xf  = (float*)act;                     // T*2048 B
  u16*   xb  = (u16*)(act + (size_t)T*2048);    // T*1024 B
  u16*   y1b = (u16*)(act + (size_t)T*3072);    // T*1024 B
  u16*   qkv = (u16*)(act + (size_t)T*4096);    // T*3072 B
  u16*   zb  = qkv;                             // alias: qkv dead once attn_ln1 ran

  const size_t wstr = (size_t)FDIM*FDIM;        // per-layer W stride (fp32 elems)

  const int chunks = NTOK / T;
  for (int c = 0; c < chunks; c++){
    const int tok0 = c*T;
    hipLaunchKernelGGL(embed_kernel, dim3(T/2), dim3(256), 0, stream, text, emb, pe, xf, xb, tok0);
    for (int lay=0; lay<6; lay++){
      hipLaunchKernelGGL((gemm_valu<0>), dim3(T/64, 24), dim3(256), 0, stream,
          (const void*)xf, Wq + (size_t)lay*wstr, Wk + (size_t)lay*wstr, Wv + (size_t)lay*wstr,
          bq + lay*FDIM, bk + lay*FDIM, bv + lay*FDIM, (const u16*)nullptr, qkv, 1536);
      hipLaunchKernelGGL(attn_ln1, dim3(T/4), dim3(256), 0, stream,
          qkv, xf, g1 + lay*FDIM, be1 + lay*FDIM, y1b);
      hipLaunchKernelGGL((gemm_valu<1>), dim3(T/64, 8), dim3(256), 0, stream,
          (const void*)y1b, Wf + (size_t)lay*wstr, (const float*)nullptr, (const float*)nullptr,
          bf_ + lay*FDIM, (const float*)nullptr, (const float*)nullptr, y1b, zb, 512);
      hipLaunchKernelGGL(ln2_kernel, dim3(T/4), dim3(256), 0, stream,
          zb, g2 + lay*FDIM, be2 + lay*FDIM, xf, xb, outp + (size_t)tok0*FDIM, (lay==5)?1:0);
    }
  }
}

// Round 6
// 1226.907 us; speedup vs baseline: 4.9538x; 4.9538x over previous
//
#include <hip/hip_runtime.h>
#include <stdint.h>

typedef unsigned short u16;
using frag8 = __attribute__((ext_vector_type(8))) short;
using f32x4 = __attribute__((ext_vector_type(4))) float;

#define NTOK 32768
#define FDIM 512

__device__ __forceinline__ float bflo(uint32_t p){ union{uint32_t u; float f;} v; v.u = p<<16; return v.f; }
__device__ __forceinline__ float bfhi(uint32_t p){ union{uint32_t u; float f;} v; v.u = p & 0xffff0000u; return v.f; }
__device__ __forceinline__ float bf1(u16 x){ union{uint32_t u; float f;} v; v.u = ((uint32_t)x)<<16; return v.f; }
__device__ __forceinline__ u16 f2bf(float f){
  union{float f; uint32_t u;} v; v.f = f;
  uint32_t u = v.u;
  u += 0x7fffu + ((u>>16)&1u);   // round-to-nearest-even
  return (u16)(u>>16);
}

__device__ __forceinline__ void async16(const void* g, void* l){
  __builtin_amdgcn_global_load_lds((const __attribute__((address_space(1))) uint32_t*)g,
                                   (__attribute__((address_space(3))) uint32_t*)l, 16, 0, 0);
}

// -------------------- embedding + positional encoding --------------------
__global__ __launch_bounds__(256) void embed_kernel(const int* __restrict__ text,
    const float* __restrict__ emb, const float* __restrict__ pe,
    float* __restrict__ xf, u16* __restrict__ xb, const int tok0){
  const int gid = blockIdx.x*256 + threadIdx.x;
  const int base = gid*4;
  const int tl = base >> 9;
  const int f  = base & 511;
  const int tg = tl + tok0;
  const int s  = tg & 511;
  const int tok = text[tg];
  const float4 e4 = *(const float4*)(emb + (size_t)tok*FDIM + f);
  const float4 p4 = *(const float4*)(pe  + (size_t)s*FDIM + f);
  const float o0 = e4.x + p4.x;
  const float o1 = e4.y + p4.y;
  const float o2 = e4.z + p4.z;
  const float o3 = e4.w + p4.w;
  float4 of; of.x=o0; of.y=o1; of.z=o2; of.w=o3;
  *(float4*)(xf + base) = of;
  ushort4 ob; ob.x=f2bf(o0); ob.y=f2bf(o1); ob.z=f2bf(o2); ob.w=f2bf(o3);
  *(ushort4*)(xb + base) = ob;
}

// -------------------- weight transpose + fp32->bf16: WT[lay][n][k], n: Wq|Wk|Wv|Wf --------------------
__global__ __launch_bounds__(256) void transpose_w(const float* __restrict__ Wq,
    const float* __restrict__ Wk, const float* __restrict__ Wv, const float* __restrict__ Wf,
    u16* __restrict__ WT){
  const int gid = blockIdx.x*256 + threadIdx.x;
  const int n   = gid & 2047;
  const int k8  = (gid>>11) & 63;
  const int lay = gid >> 17;
  const float* src; int col;
  if      (n <  512){ src = Wq; col = n;      }
  else if (n < 1024){ src = Wk; col = n-512;  }
  else if (n < 1536){ src = Wv; col = n-1024; }
  else              { src = Wf; col = n-1536; }
  src += (size_t)lay*FDIM*FDIM;
  u16 vals[8] __attribute__((aligned(16)));
  #pragma unroll
  for (int i=0;i<8;i++) vals[i] = f2bf(src[(size_t)(k8*8+i)*FDIM + col]);
  *(int4*)(WT + ((size_t)lay*2048 + n)*FDIM + k8*8) = *(const int4*)vals;
}

// -------------------- MFMA GEMM: C[M x ldC] = A[M x 512] * BT[n][k]^T + bias (+resid) --------------------
// MODE 0: qkv (fp32 bias b0/b1/b2 by column range), MODE 1: ff (fp32 bias b0 + bf16 resid)
template<int MODE>
__global__ __launch_bounds__(256) void gemm_mfma(
    const u16* __restrict__ A, const u16* __restrict__ BT,
    const float* __restrict__ b0, const float* __restrict__ b1, const float* __restrict__ b2,
    const u16* __restrict__ resid, u16* __restrict__ C, int ldC){
  __shared__ __attribute__((aligned(16))) short As[128*32];
  __shared__ __attribute__((aligned(16))) short Bs[128*32];
  const int tid = threadIdx.x;
  const int w = tid>>6, l = tid&63;
  const int m0 = blockIdx.x*128;
  const int n0 = blockIdx.y*128;
  const int quad = l>>4, lm = l&15;
  const int wm = (w&1)*64, wn = (w>>1)*64;

  f32x4 acc[4][4];
  #pragma unroll
  for (int i=0;i<4;i++)
    #pragma unroll
    for (int j=0;j<4;j++){ f32x4 z = {0.f,0.f,0.f,0.f}; acc[i][j] = z; }

  const int cA = w*64 + l;                 // 16B chunk id; row = c>>2, sub = c&3
  const char* Ab = (const char*)(A  + (size_t)m0*FDIM) + (size_t)(cA>>2)*1024 + (cA&3)*16;
  const char* Bb = (const char*)(BT + (size_t)n0*FDIM) + (size_t)(cA>>2)*1024 + (cA&3)*16;
  char* ldsA = (char*)As + w*1024;         // wave-uniform LDS base; HW adds lane*16
  char* ldsB = (char*)Bs + w*1024;

  for (int kb=0; kb<512; kb+=32){
    __syncthreads();
    async16(Ab + kb*2,         ldsA);
    async16(Ab + kb*2 + 65536, ldsA + 4096);
    async16(Bb + kb*2,         ldsB);
    async16(Bb + kb*2 + 65536, ldsB + 4096);
    __syncthreads();
    frag8 af[4], bfrg[4];
    #pragma unroll
    for (int i=0;i<4;i++) af[i]   = *(const frag8*)(As + (wm+i*16+lm)*32 + quad*8);
    #pragma unroll
    for (int j=0;j<4;j++) bfrg[j] = *(const frag8*)(Bs + (wn+j*16+lm)*32 + quad*8);
    #pragma unroll
    for (int i=0;i<4;i++)
      #pragma unroll
      for (int j=0;j<4;j++)
        acc[i][j] = __builtin_amdgcn_mfma_f32_16x16x32_bf16(af[i], bfrg[j], acc[i][j], 0,0,0);
  }

  float bias[4]; int cols[4];
  #pragma unroll
  for (int j=0;j<4;j++){
    const int c = n0 + wn + j*16 + lm;
    cols[j] = c;
    if (MODE==0) bias[j] = (c<512 ? b0[c] : (c<1024 ? b1[c-512] : b2[c-1024]));
    else         bias[j] = b0[c];
  }
  #pragma unroll
  for (int i=0;i<4;i++){
    const int rbase = m0 + wm + i*16 + quad*4;
    #pragma unroll
    for (int r=0;r<4;r++){
      const size_t row = (size_t)(rbase + r);
      #pragma unroll
      for (int j=0;j<4;j++){
        float v = acc[i][j][r] + bias[j];
        if (MODE==1) v += bf1(resid[row*FDIM + cols[j]]);
        C[row*(size_t)ldC + cols[j]] = f2bf(v);
      }
    }
  }
}

// -------------------- per-token head-attention + residual + LN1 (1 wave = 1 token) --------------------
__global__ __launch_bounds__(256) void attn_ln1(const u16* __restrict__ qkvb,
    const float* __restrict__ xf, const float* __restrict__ gam, const float* __restrict__ bet,
    u16* __restrict__ y1b){
  __shared__ __attribute__((aligned(16))) u16 sQ[4][1536];
  __shared__ float sWt[4][64];
  const int tid = threadIdx.x, w = tid>>6, l = tid&63;
  const int t = blockIdx.x*4 + w;
  {
    const int4* src = (const int4*)(qkvb + (size_t)t*1536);
    int4* dst = (int4*)(&sQ[w][0]);
    #pragma unroll
    for (int i=0;i<3;i++) dst[i*64 + l] = src[i*64 + l];
  }
  __syncthreads();
  const int h = l>>3, g = l&7;
  const u16* qrow = &sQ[w][h*64];
  const u16* krow = &sQ[w][512 + g*64];
  float sc = 0.f;
  const int dstart = (l&31)*2;
  #pragma unroll
  for (int i=0;i<32;i++){
    const int d = (dstart + 2*i) & 63;
    const uint32_t qp = *(const uint32_t*)(qrow + d);
    const uint32_t kp = *(const uint32_t*)(krow + d);
    sc += bflo(qp)*bflo(kp) + bfhi(qp)*bfhi(kp);
  }
  float mx = sc;
  mx = fmaxf(mx, __shfl_xor(mx,1));
  mx = fmaxf(mx, __shfl_xor(mx,2));
  mx = fmaxf(mx, __shfl_xor(mx,4));
  const float e = __expf(sc - mx);
  float ssum = e;
  ssum += __shfl_xor(ssum,1);
  ssum += __shfl_xor(ssum,2);
  ssum += __shfl_xor(ssum,4);
  sWt[w][l] = e / ssum;
  __syncthreads();
  float wt[8];
  #pragma unroll
  for (int gg=0;gg<8;gg++) wt[gg] = sWt[w][h*8+gg];
  float att[8] = {0,0,0,0,0,0,0,0};
  const int d0 = (l&7)*8;
  #pragma unroll
  for (int gg=0;gg<8;gg++){
    const int4 vv = *(const int4*)(&sQ[w][1024 + gg*64 + d0]);
    const uint32_t* vp = (const uint32_t*)&vv;
    #pragma unroll
    for (int p=0;p<4;p++){
      att[2*p]   += wt[gg]*bflo(vp[p]);
      att[2*p+1] += wt[gg]*bfhi(vp[p]);
    }
  }
  const size_t rb = (size_t)t*FDIM + l*8;
  float y[8]; float s1=0.f, s2=0.f;
  const float4 x0 = *(const float4*)(xf + rb);
  const float4 x1 = *(const float4*)(xf + rb + 4);
  y[0]=att[0]+x0.x; y[1]=att[1]+x0.y; y[2]=att[2]+x0.z; y[3]=att[3]+x0.w;
  y[4]=att[4]+x1.x; y[5]=att[5]+x1.y; y[6]=att[6]+x1.z; y[7]=att[7]+x1.w;
  #pragma unroll
  for (int j=0;j<8;j++){ s1 += y[j]; s2 += y[j]*y[j]; }
  #pragma unroll
  for (int off=1; off<64; off<<=1){ s1 += __shfl_xor(s1,off); s2 += __shfl_xor(s2,off); }
  const float mean = s1*(1.f/512.f);
  const float var  = s2*(1.f/512.f) - mean*mean;
  const float rstd = rsqrtf(var + 1e-5f);
  const float4 g0 = *(const float4*)(gam + l*8);
  const float4 g1v = *(const float4*)(gam + l*8 + 4);
  const float4 b0v = *(const float4*)(bet + l*8);
  const float4 b1v = *(const float4*)(bet + l*8 + 4);
  float of[8];
  of[0]=(y[0]-mean)*rstd*g0.x + b0v.x;
  of[1]=(y[1]-mean)*rstd*g0.y + b0v.y;
  of[2]=(y[2]-mean)*rstd*g0.z + b0v.z;
  of[3]=(y[3]-mean)*rstd*g0.w + b0v.w;
  of[4]=(y[4]-mean)*rstd*g1v.x + b1v.x;
  of[5]=(y[5]-mean)*rstd*g1v.y + b1v.y;
  of[6]=(y[6]-mean)*rstd*g1v.z + b1v.z;
  of[7]=(y[7]-mean)*rstd*g1v.w + b1v.w;
  u16 ob[8] __attribute__((aligned(16)));
  #pragma unroll
  for (int j=0;j<8;j++) ob[j] = f2bf(of[j]);
  *(int4*)(y1b + rb) = *(const int4*)ob;
}

// -------------------- LN2 over z; final layer writes FP32 output --------------------
__global__ __launch_bounds__(256) void ln2_kernel(const u16* __restrict__ z,
    const float* __restrict__ gam, const float* __restrict__ bet,
    float* __restrict__ xf, u16* __restrict__ xb, float* __restrict__ outp, const int final_){
  const int tid = threadIdx.x, w = tid>>6, l = tid&63;
  const int t = blockIdx.x*4 + w;
  const size_t rb = (size_t)t*FDIM + l*8;
  const int4 zv = *(const int4*)(z + rb);
  const uint32_t* zp = (const uint32_t*)&zv;
  float y[8];
  #pragma unroll
  for (int p=0;p<4;p++){ y[2*p]=bflo(zp[p]); y[2*p+1]=bfhi(zp[p]); }
  float s1=0.f, s2=0.f;
  #pragma unroll
  for (int j=0;j<8;j++){ s1+=y[j]; s2+=y[j]*y[j]; }
  #pragma unroll
  for (int off=1; off<64; off<<=1){ s1 += __shfl_xor(s1,off); s2 += __shfl_xor(s2,off); }
  const float mean = s1*(1.f/512.f);
  const float var  = s2*(1.f/512.f) - mean*mean;
  const float rstd = rsqrtf(var + 1e-5f);
  const float4 g0 = *(const float4*)(gam + l*8);
  const float4 g1v = *(const float4*)(gam + l*8 + 4);
  const float4 b0v = *(const float4*)(bet + l*8);
  const float4 b1v = *(const float4*)(bet + l*8 + 4);
  float of[8];
  of[0]=(y[0]-mean)*rstd*g0.x + b0v.x;
  of[1]=(y[1]-mean)*rstd*g0.y + b0v.y;
  of[2]=(y[2]-mean)*rstd*g0.z + b0v.z;
  of[3]=(y[3]-mean)*rstd*g0.w + b0v.w;
  of[4]=(y[4]-mean)*rstd*g1v.x + b1v.x;
  of[5]=(y[5]-mean)*rstd*g1v.y + b1v.y;
  of[6]=(y[6]-mean)*rstd*g1v.z + b1v.z;
  of[7]=(y[7]-mean)*rstd*g1v.w + b1v.w;
  float4 o0; o0.x=of[0]; o0.y=of[1]; o0.z=of[2]; o0.w=of[3];
  float4 o1; o1.x=of[4]; o1.y=of[5]; o1.z=of[6]; o1.w=of[7];
  if (final_){
    *(float4*)(outp + rb) = o0;              // FP32 output per harness contract
    *(float4*)(outp + rb + 4) = o1;
  } else {
    *(float4*)(xf + rb) = o0;
    *(float4*)(xf + rb + 4) = o1;
    u16 ob[8] __attribute__((aligned(16)));
    #pragma unroll
    for (int j=0;j<8;j++) ob[j] = f2bf(of[j]);
    *(int4*)(xb + rb) = *(const int4*)ob;
  }
}

extern "C" void kernel_launch(void* const* d_in, const int* in_sizes, int n_in,
                              void* d_out, int out_size, void* d_ws, size_t ws_size,
                              hipStream_t stream){
  const int*   text = (const int*)d_in[0];
  const float* emb = (const float*)d_in[1];
  const float* pe  = (const float*)d_in[2];
  const float* Wq  = (const float*)d_in[3];
  const float* bq  = (const float*)d_in[4];
  const float* Wk  = (const float*)d_in[5];
  const float* bk  = (const float*)d_in[6];
  const float* Wv  = (const float*)d_in[7];
  const float* bv  = (const float*)d_in[8];
  const float* g1  = (const float*)d_in[9];
  const float* be1 = (const float*)d_in[10];
  const float* Wf  = (const float*)d_in[11];
  const float* bf_ = (const float*)d_in[12];
  const float* g2  = (const float*)d_in[13];
  const float* be2 = (const float*)d_in[14];
  float* outp = (float*)d_out;               // reference output dtype = float32

  // ---- layout: WT 12.6 MB + per-token {xf 2048 + xb 1024 + y1b 1024 + qkv 3072} = 7168 B
  const size_t wtB = (size_t)6*2048*512*2;
  int T = 16384;
  while (T > 2048 && wtB + (size_t)T*7168 > ws_size) T >>= 1;

  char* ws = (char*)d_ws;
  u16*   WT  = (u16*)ws;
  char*  act = ws + wtB;
  float* xf  = (float*)act;                     // T*2048 B
  u16*   xb  = (u16*)(act + (size_t)T*2048);    // T*1024 B
  u16*   y1b = (u16*)(act + (size_t)T*3072);    // T*1024 B
  u16*   qkv = (u16*)(act + (size_t)T*4096);    // T*3072 B
  u16*   zb  = qkv;                             // alias: qkv dead once attn_ln1 ran

  hipLaunchKernelGGL(transpose_w, dim3(3072), dim3(256), 0, stream, Wq, Wk, Wv, Wf, WT);

  const int chunks = NTOK / T;
  for (int c = 0; c < chunks; c++){
    const int tok0 = c*T;
    hipLaunchKernelGGL(embed_kernel, dim3(T/2), dim3(256), 0, stream, text, emb, pe, xf, xb, tok0);
    for (int lay=0; lay<6; lay++){
      const u16* WTl = WT + (size_t)lay*2048*FDIM;
      hipLaunchKernelGGL((gemm_mfma<0>), dim3(T/128, 12), dim3(256), 0, stream,
          xb, WTl, bq + lay*FDIM, bk + lay*FDIM, bv + lay*FDIM, (const u16*)nullptr, qkv, 1536);
      hipLaunchKernelGGL(attn_ln1, dim3(T/4), dim3(256), 0, stream,
          qkv, xf, g1 + lay*FDIM, be1 + lay*FDIM, y1b);
      hipLaunchKernelGGL((gemm_mfma<1>), dim3(T/128, 4), dim3(256), 0, stream,
          y1b, WTl + (size_t)1536*FDIM, bf_ + lay*FDIM, (const float*)nullptr, (const float*)nullptr,
          y1b, zb, 512);
      hipLaunchKernelGGL(ln2_kernel, dim3(T/4), dim3(256), 0, stream,
          zb, g2 + lay*FDIM, be2 + lay*FDIM, xf, xb, outp + (size_t)tok0*FDIM, (lay==5)?1:0);
    }
  }
}

// Round 7
// 1094.452 us; speedup vs baseline: 5.5534x; 1.1210x over previous
//
#include <hip/hip_runtime.h>
#include <stdint.h>

typedef unsigned short u16;
using frag8 = __attribute__((ext_vector_type(8))) short;
using f32x4 = __attribute__((ext_vector_type(4))) float;

#define NTOK 32768
#define FDIM 512

__device__ __forceinline__ float bflo(uint32_t p){ union{uint32_t u; float f;} v; v.u = p<<16; return v.f; }
__device__ __forceinline__ float bfhi(uint32_t p){ union{uint32_t u; float f;} v; v.u = p & 0xffff0000u; return v.f; }
__device__ __forceinline__ float bf1(u16 x){ union{uint32_t u; float f;} v; v.u = ((uint32_t)x)<<16; return v.f; }
__device__ __forceinline__ u16 f2bf(float f){
  union{float f; uint32_t u;} v; v.f = f;
  uint32_t u = v.u;
  u += 0x7fffu + ((u>>16)&1u);   // round-to-nearest-even
  return (u16)(u>>16);
}

__device__ __forceinline__ void async16(const void* g, void* l){
  __builtin_amdgcn_global_load_lds((const __attribute__((address_space(1))) uint32_t*)g,
                                   (__attribute__((address_space(3))) uint32_t*)l, 16, 0, 0);
}

// -------------------- embedding + positional encoding (bf16 x only) --------------------
__global__ __launch_bounds__(256) void embed_kernel(const int* __restrict__ text,
    const float* __restrict__ emb, const float* __restrict__ pe,
    u16* __restrict__ xb, const int tok0){
  const int gid = blockIdx.x*256 + threadIdx.x;
  const int base = gid*4;
  const int tl = base >> 9;
  const int f  = base & 511;
  const int tg = tl + tok0;
  const int s  = tg & 511;
  const int tok = text[tg];
  const float4 e4 = *(const float4*)(emb + (size_t)tok*FDIM + f);
  const float4 p4 = *(const float4*)(pe  + (size_t)s*FDIM + f);
  ushort4 ob;
  ob.x = f2bf(e4.x + p4.x);
  ob.y = f2bf(e4.y + p4.y);
  ob.z = f2bf(e4.z + p4.z);
  ob.w = f2bf(e4.w + p4.w);
  *(ushort4*)(xb + base) = ob;
}

// -------------------- weight transpose + fp32->bf16: WT[lay][n][k], n: Wq|Wk|Wv|Wf --------------------
__global__ __launch_bounds__(256) void transpose_w(const float* __restrict__ Wq,
    const float* __restrict__ Wk, const float* __restrict__ Wv, const float* __restrict__ Wf,
    u16* __restrict__ WT){
  const int gid = blockIdx.x*256 + threadIdx.x;
  const int n   = gid & 2047;
  const int k8  = (gid>>11) & 63;
  const int lay = gid >> 17;
  const float* src; int col;
  if      (n <  512){ src = Wq; col = n;      }
  else if (n < 1024){ src = Wk; col = n-512;  }
  else if (n < 1536){ src = Wv; col = n-1024; }
  else              { src = Wf; col = n-1536; }
  src += (size_t)lay*FDIM*FDIM;
  u16 vals[8] __attribute__((aligned(16)));
  #pragma unroll
  for (int i=0;i<8;i++) vals[i] = f2bf(src[(size_t)(k8*8+i)*FDIM + col]);
  *(int4*)(WT + ((size_t)lay*2048 + n)*FDIM + k8*8) = *(const int4*)vals;
}

// -------------------- MFMA GEMM (qkv): C[M x 1536] = A[M x 512] * BT^T + bias --------------------
__global__ __launch_bounds__(256) void gemm_qkv(
    const u16* __restrict__ A, const u16* __restrict__ BT,
    const float* __restrict__ b0, const float* __restrict__ b1, const float* __restrict__ b2,
    u16* __restrict__ C){
  __shared__ __attribute__((aligned(16))) short As[128*32];
  __shared__ __attribute__((aligned(16))) short Bs[128*32];
  const int tid = threadIdx.x;
  const int w = tid>>6, l = tid&63;
  const int m0 = blockIdx.x*128;
  const int n0 = blockIdx.y*128;
  const int quad = l>>4, lm = l&15;
  const int wm = (w&1)*64, wn = (w>>1)*64;

  f32x4 acc[4][4];
  #pragma unroll
  for (int i=0;i<4;i++)
    #pragma unroll
    for (int j=0;j<4;j++){ f32x4 z = {0.f,0.f,0.f,0.f}; acc[i][j] = z; }

  const int cA = w*64 + l;                 // 16B chunk id; row = c>>2, sub = c&3
  const char* Ab = (const char*)(A  + (size_t)m0*FDIM) + (size_t)(cA>>2)*1024 + (cA&3)*16;
  const char* Bb = (const char*)(BT + (size_t)n0*FDIM) + (size_t)(cA>>2)*1024 + (cA&3)*16;
  char* ldsA = (char*)As + w*1024;         // wave-uniform LDS base; HW adds lane*16
  char* ldsB = (char*)Bs + w*1024;

  for (int kb=0; kb<512; kb+=32){
    __syncthreads();
    async16(Ab + kb*2,         ldsA);
    async16(Ab + kb*2 + 65536, ldsA + 4096);
    async16(Bb + kb*2,         ldsB);
    async16(Bb + kb*2 + 65536, ldsB + 4096);
    __syncthreads();
    frag8 af[4], bfrg[4];
    #pragma unroll
    for (int i=0;i<4;i++) af[i]   = *(const frag8*)(As + (wm+i*16+lm)*32 + quad*8);
    #pragma unroll
    for (int j=0;j<4;j++) bfrg[j] = *(const frag8*)(Bs + (wn+j*16+lm)*32 + quad*8);
    #pragma unroll
    for (int i=0;i<4;i++)
      #pragma unroll
      for (int j=0;j<4;j++)
        acc[i][j] = __builtin_amdgcn_mfma_f32_16x16x32_bf16(af[i], bfrg[j], acc[i][j], 0,0,0);
  }

  float bias[4]; int cols[4];
  #pragma unroll
  for (int j=0;j<4;j++){
    const int c = n0 + wn + j*16 + lm;
    cols[j] = c;
    bias[j] = (c<512 ? b0[c] : (c<1024 ? b1[c-512] : b2[c-1024]));
  }
  #pragma unroll
  for (int i=0;i<4;i++){
    const int rbase = m0 + wm + i*16 + quad*4;
    #pragma unroll
    for (int r=0;r<4;r++){
      const size_t row = (size_t)(rbase + r);
      #pragma unroll
      for (int j=0;j<4;j++){
        C[row*1536 + cols[j]] = f2bf(acc[i][j][r] + bias[j]);
      }
    }
  }
}

// -------------------- fused FF GEMM + bias + residual + LN2 --------------------
// Tile: 32 tokens x full 512 cols. acc row = mi*16+quad*4+r, col = w*128+j*16+lm.
// A-frags read directly from global (32KB tile is L1/L2-resident). Residual = A itself.
// FINAL=0: write bf16 xbo (next-layer x). FINAL=1: write fp32 outp.
template<int FINAL>
__global__ __launch_bounds__(256) void gemm_ff_ln2(
    const u16* __restrict__ A, const u16* __restrict__ BT,
    const float* __restrict__ bias, const float* __restrict__ gam, const float* __restrict__ bet,
    u16* __restrict__ xbo, float* __restrict__ outp){
  __shared__ __attribute__((aligned(16))) u16 Bs[512*32];   // [n][k-chunk] rows of 64B
  __shared__ float sP1[32][4];
  __shared__ float sP2[32][4];
  const int tid = threadIdx.x, w = tid>>6, l = tid&63;
  const int quad = l>>4, lm = l&15;
  const int m0 = blockIdx.x*32;
  const u16* Arow0 = A + (size_t)m0*FDIM;

  f32x4 acc[2][8];
  #pragma unroll
  for (int i=0;i<2;i++)
    #pragma unroll
    for (int j=0;j<8;j++){ f32x4 z = {0.f,0.f,0.f,0.f}; acc[i][j] = z; }

  const int cB = w*64 + l;
  const char* Bb = (const char*)BT;
  char* ldsB = (char*)Bs + w*1024;

  for (int kb=0; kb<512; kb+=32){
    __syncthreads();                       // Bs free for restage
    #pragma unroll
    for (int i=0;i<8;i++){
      const int c = cB + i*256;            // chunk: n = c>>2, sub = c&3
      async16(Bb + (size_t)(c>>2)*1024 + kb*2 + (c&3)*16, ldsB + i*4096);
    }
    __syncthreads();
    frag8 af[2], bfr[8];
    #pragma unroll
    for (int i=0;i<2;i++)
      af[i] = *(const frag8*)(Arow0 + (size_t)(i*16+lm)*FDIM + kb + quad*8);
    #pragma unroll
    for (int j=0;j<8;j++)
      bfr[j] = *(const frag8*)(Bs + (w*128+j*16+lm)*32 + quad*8);
    #pragma unroll
    for (int i=0;i<2;i++)
      #pragma unroll
      for (int j=0;j<8;j++)
        acc[i][j] = __builtin_amdgcn_mfma_f32_16x16x32_bf16(af[i], bfr[j], acc[i][j], 0,0,0);
  }

  // fold bias + residual (residual = A row itself)
  float gv[8], bv[8];
  #pragma unroll
  for (int j=0;j<8;j++){
    const int col = w*128 + j*16 + lm;
    gv[j] = gam[col];  bv[j] = bet[col];
    const float bs = bias[col];
    #pragma unroll
    for (int i=0;i<2;i++)
      #pragma unroll
      for (int r=0;r<4;r++){
        const int row = i*16 + quad*4 + r;
        acc[i][j][r] += bs + bf1(Arow0[(size_t)row*FDIM + col]);
      }
  }
  // per-row partial sums over this wave's 128 cols
  float ps1[2][4], ps2[2][4];
  #pragma unroll
  for (int i=0;i<2;i++)
    #pragma unroll
    for (int r=0;r<4;r++){ ps1[i][r]=0.f; ps2[i][r]=0.f; }
  #pragma unroll
  for (int i=0;i<2;i++)
    #pragma unroll
    for (int j=0;j<8;j++)
      #pragma unroll
      for (int r=0;r<4;r++){
        const float v = acc[i][j][r];
        ps1[i][r] += v; ps2[i][r] += v*v;
      }
  #pragma unroll
  for (int off=1; off<16; off<<=1){   // reduce across the 16 lanes of each quad
    #pragma unroll
    for (int i=0;i<2;i++)
      #pragma unroll
      for (int r=0;r<4;r++){
        ps1[i][r] += __shfl_xor(ps1[i][r], off);
        ps2[i][r] += __shfl_xor(ps2[i][r], off);
      }
  }
  if (lm == 0){
    #pragma unroll
    for (int i=0;i<2;i++)
      #pragma unroll
      for (int r=0;r<4;r++){
        const int row = i*16 + quad*4 + r;
        sP1[row][w] = ps1[i][r];
        sP2[row][w] = ps2[i][r];
      }
  }
  __syncthreads();
  #pragma unroll
  for (int i=0;i<2;i++){
    #pragma unroll
    for (int r=0;r<4;r++){
      const int row = i*16 + quad*4 + r;
      const float s1 = sP1[row][0]+sP1[row][1]+sP1[row][2]+sP1[row][3];
      const float s2 = sP2[row][0]+sP2[row][1]+sP2[row][2]+sP2[row][3];
      const float mean = s1*(1.f/512.f);
      const float var  = s2*(1.f/512.f) - mean*mean;
      const float rstd = rsqrtf(var + 1e-5f);
      const size_t gr = (size_t)(m0 + row)*FDIM;
      #pragma unroll
      for (int j=0;j<8;j++){
        const int col = w*128 + j*16 + lm;
        const float o = (acc[i][j][r]-mean)*rstd*gv[j] + bv[j];
        if (FINAL) outp[gr + col] = o;
        else       xbo[gr + col]  = f2bf(o);
      }
    }
  }
}

// -------------------- per-token head-attention + residual(bf16) + LN1 (1 wave = 1 token) --------------------
__global__ __launch_bounds__(256) void attn_ln1(const u16* __restrict__ qkvb,
    const u16* __restrict__ xb, const float* __restrict__ gam, const float* __restrict__ bet,
    u16* __restrict__ y1b){
  __shared__ __attribute__((aligned(16))) u16 sQ[4][1536];
  __shared__ float sWt[4][64];
  const int tid = threadIdx.x, w = tid>>6, l = tid&63;
  const int t = blockIdx.x*4 + w;
  {
    const int4* src = (const int4*)(qkvb + (size_t)t*1536);
    int4* dst = (int4*)(&sQ[w][0]);
    #pragma unroll
    for (int i=0;i<3;i++) dst[i*64 + l] = src[i*64 + l];
  }
  __syncthreads();
  const int h = l>>3, g = l&7;
  const u16* qrow = &sQ[w][h*64];
  const u16* krow = &sQ[w][512 + g*64];
  float sc = 0.f;
  const int dstart = (l&31)*2;
  #pragma unroll
  for (int i=0;i<32;i++){
    const int d = (dstart + 2*i) & 63;
    const uint32_t qp = *(const uint32_t*)(qrow + d);
    const uint32_t kp = *(const uint32_t*)(krow + d);
    sc += bflo(qp)*bflo(kp) + bfhi(qp)*bfhi(kp);
  }
  float mx = sc;
  mx = fmaxf(mx, __shfl_xor(mx,1));
  mx = fmaxf(mx, __shfl_xor(mx,2));
  mx = fmaxf(mx, __shfl_xor(mx,4));
  const float e = __expf(sc - mx);
  float ssum = e;
  ssum += __shfl_xor(ssum,1);
  ssum += __shfl_xor(ssum,2);
  ssum += __shfl_xor(ssum,4);
  sWt[w][l] = e / ssum;
  __syncthreads();
  float wt[8];
  #pragma unroll
  for (int gg=0;gg<8;gg++) wt[gg] = sWt[w][h*8+gg];
  float att[8] = {0,0,0,0,0,0,0,0};
  const int d0 = (l&7)*8;
  #pragma unroll
  for (int gg=0;gg<8;gg++){
    const int4 vv = *(const int4*)(&sQ[w][1024 + gg*64 + d0]);
    const uint32_t* vp = (const uint32_t*)&vv;
    #pragma unroll
    for (int p=0;p<4;p++){
      att[2*p]   += wt[gg]*bflo(vp[p]);
      att[2*p+1] += wt[gg]*bfhi(vp[p]);
    }
  }
  const size_t rb = (size_t)t*FDIM + l*8;
  const int4 xv = *(const int4*)(xb + rb);
  const uint32_t* xp = (const uint32_t*)&xv;
  float y[8]; float s1=0.f, s2=0.f;
  #pragma unroll
  for (int p=0;p<4;p++){
    y[2*p]   = att[2*p]   + bflo(xp[p]);
    y[2*p+1] = att[2*p+1] + bfhi(xp[p]);
  }
  #pragma unroll
  for (int j=0;j<8;j++){ s1 += y[j]; s2 += y[j]*y[j]; }
  #pragma unroll
  for (int off=1; off<64; off<<=1){ s1 += __shfl_xor(s1,off); s2 += __shfl_xor(s2,off); }
  const float mean = s1*(1.f/512.f);
  const float var  = s2*(1.f/512.f) - mean*mean;
  const float rstd = rsqrtf(var + 1e-5f);
  const float4 g0 = *(const float4*)(gam + l*8);
  const float4 g1v = *(const float4*)(gam + l*8 + 4);
  const float4 b0v = *(const float4*)(bet + l*8);
  const float4 b1v = *(const float4*)(bet + l*8 + 4);
  float of[8];
  of[0]=(y[0]-mean)*rstd*g0.x + b0v.x;
  of[1]=(y[1]-mean)*rstd*g0.y + b0v.y;
  of[2]=(y[2]-mean)*rstd*g0.z + b0v.z;
  of[3]=(y[3]-mean)*rstd*g0.w + b0v.w;
  of[4]=(y[4]-mean)*rstd*g1v.x + b1v.x;
  of[5]=(y[5]-mean)*rstd*g1v.y + b1v.y;
  of[6]=(y[6]-mean)*rstd*g1v.z + b1v.z;
  of[7]=(y[7]-mean)*rstd*g1v.w + b1v.w;
  u16 ob[8] __attribute__((aligned(16)));
  #pragma unroll
  for (int j=0;j<8;j++) ob[j] = f2bf(of[j]);
  *(int4*)(y1b + rb) = *(const int4*)ob;
}

extern "C" void kernel_launch(void* const* d_in, const int* in_sizes, int n_in,
                              void* d_out, int out_size, void* d_ws, size_t ws_size,
                              hipStream_t stream){
  const int*   text = (const int*)d_in[0];
  const float* emb = (const float*)d_in[1];
  const float* pe  = (const float*)d_in[2];
  const float* Wq  = (const float*)d_in[3];
  const float* bq  = (const float*)d_in[4];
  const float* Wk  = (const float*)d_in[5];
  const float* bk  = (const float*)d_in[6];
  const float* Wv  = (const float*)d_in[7];
  const float* bv  = (const float*)d_in[8];
  const float* g1  = (const float*)d_in[9];
  const float* be1 = (const float*)d_in[10];
  const float* Wf  = (const float*)d_in[11];
  const float* bf_ = (const float*)d_in[12];
  const float* g2  = (const float*)d_in[13];
  const float* be2 = (const float*)d_in[14];
  float* outp = (float*)d_out;               // reference output dtype = float32

  // ---- layout: WT 12.6 MB + per-token {xb 1024 + y1b 1024 + qkv 3072} = 5120 B
  const size_t wtB = (size_t)6*2048*512*2;
  int T = NTOK;                               // single chunk if ws permits
  while (T > 2048 && wtB + (size_t)T*5120 > ws_size) T >>= 1;

  char* ws = (char*)d_ws;
  u16*   WT  = (u16*)ws;
  char*  act = ws + wtB;
  u16*   xb  = (u16*)act;                       // T*1024 B
  u16*   y1b = (u16*)(act + (size_t)T*1024);    // T*1024 B
  u16*   qkv = (u16*)(act + (size_t)T*2048);    // T*3072 B

  hipLaunchKernelGGL(transpose_w, dim3(3072), dim3(256), 0, stream, Wq, Wk, Wv, Wf, WT);

  const int chunks = NTOK / T;
  for (int c = 0; c < chunks; c++){
    const int tok0 = c*T;
    hipLaunchKernelGGL(embed_kernel, dim3(T/2), dim3(256), 0, stream, text, emb, pe, xb, tok0);
    for (int lay=0; lay<6; lay++){
      const u16* WTl = WT + (size_t)lay*2048*FDIM;
      hipLaunchKernelGGL(gemm_qkv, dim3(T/128, 12), dim3(256), 0, stream,
          xb, WTl, bq + lay*FDIM, bk + lay*FDIM, bv + lay*FDIM, qkv);
      hipLaunchKernelGGL(attn_ln1, dim3(T/4), dim3(256), 0, stream,
          qkv, xb, g1 + lay*FDIM, be1 + lay*FDIM, y1b);
      if (lay < 5){
        hipLaunchKernelGGL((gemm_ff_ln2<0>), dim3(T/32), dim3(256), 0, stream,
            y1b, WTl + (size_t)1536*FDIM, bf_ + lay*FDIM, g2 + lay*FDIM, be2 + lay*FDIM,
            xb, (float*)nullptr);
      } else {
        hipLaunchKernelGGL((gemm_ff_ln2<1>), dim3(T/32), dim3(256), 0, stream,
            y1b, WTl + (size_t)1536*FDIM, bf_ + lay*FDIM, g2 + lay*FDIM, be2 + lay*FDIM,
            (u16*)nullptr, outp + (size_t)tok0*FDIM);
      }
    }
  }
}

// Round 8
// 1031.877 us; speedup vs baseline: 5.8901x; 1.0606x over previous
//
#include <hip/hip_runtime.h>
#include <stdint.h>

typedef unsigned short u16;
using frag8 = __attribute__((ext_vector_type(8))) short;
using f32x4 = __attribute__((ext_vector_type(4))) float;

#define NTOK 32768
#define FDIM 512

__device__ __forceinline__ float bflo(uint32_t p){ union{uint32_t u; float f;} v; v.u = p<<16; return v.f; }
__device__ __forceinline__ float bfhi(uint32_t p){ union{uint32_t u; float f;} v; v.u = p & 0xffff0000u; return v.f; }
__device__ __forceinline__ float bf1(u16 x){ union{uint32_t u; float f;} v; v.u = ((uint32_t)x)<<16; return v.f; }
__device__ __forceinline__ u16 f2bf(float f){
  union{float f; uint32_t u;} v; v.f = f;
  uint32_t u = v.u;
  u += 0x7fffu + ((u>>16)&1u);   // round-to-nearest-even
  return (u16)(u>>16);
}

__device__ __forceinline__ void async16(const void* g, void* l){
  __builtin_amdgcn_global_load_lds((const __attribute__((address_space(1))) uint32_t*)g,
                                   (__attribute__((address_space(3))) uint32_t*)l, 16, 0, 0);
}

// -------------------- embedding + positional encoding (bf16 x only) --------------------
__global__ __launch_bounds__(256) void embed_kernel(const int* __restrict__ text,
    const float* __restrict__ emb, const float* __restrict__ pe,
    u16* __restrict__ xb, const int tok0){
  const int gid = blockIdx.x*256 + threadIdx.x;
  const int base = gid*4;
  const int tl = base >> 9;
  const int f  = base & 511;
  const int tg = tl + tok0;
  const int s  = tg & 511;
  const int tok = text[tg];
  const float4 e4 = *(const float4*)(emb + (size_t)tok*FDIM + f);
  const float4 p4 = *(const float4*)(pe  + (size_t)s*FDIM + f);
  ushort4 ob;
  ob.x = f2bf(e4.x + p4.x);
  ob.y = f2bf(e4.y + p4.y);
  ob.z = f2bf(e4.z + p4.z);
  ob.w = f2bf(e4.w + p4.w);
  *(ushort4*)(xb + base) = ob;
}

// -------------------- weight transpose + fp32->bf16: WT[lay][n][k], n: Wq|Wk|Wv|Wf --------------------
__global__ __launch_bounds__(256) void transpose_w(const float* __restrict__ Wq,
    const float* __restrict__ Wk, const float* __restrict__ Wv, const float* __restrict__ Wf,
    u16* __restrict__ WT){
  const int gid = blockIdx.x*256 + threadIdx.x;
  const int n   = gid & 2047;
  const int k8  = (gid>>11) & 63;
  const int lay = gid >> 17;
  const float* src; int col;
  if      (n <  512){ src = Wq; col = n;      }
  else if (n < 1024){ src = Wk; col = n-512;  }
  else if (n < 1536){ src = Wv; col = n-1024; }
  else              { src = Wf; col = n-1536; }
  src += (size_t)lay*FDIM*FDIM;
  u16 vals[8] __attribute__((aligned(16)));
  #pragma unroll
  for (int i=0;i<8;i++) vals[i] = f2bf(src[(size_t)(k8*8+i)*FDIM + col]);
  *(int4*)(WT + ((size_t)lay*2048 + n)*FDIM + k8*8) = *(const int4*)vals;
}

// -------------------- MFMA GEMM 128x128 (m97 structure): C = A[Mx512]*BT^T + bias (+resid=A-row) ----
// MODE 0: qkv, ldC=1536, fp32 bias b0/b1/b2 by column range.
// MODE 1: ff,  ldC=512,  fp32 bias b0 + bf16 residual from resid (== A).
template<int MODE>
__global__ __launch_bounds__(256) void gemm_mfma(
    const u16* __restrict__ A, const u16* __restrict__ BT,
    const float* __restrict__ b0, const float* __restrict__ b1, const float* __restrict__ b2,
    const u16* __restrict__ resid, u16* __restrict__ C, int ldC){
  __shared__ __attribute__((aligned(16))) short As[128*32];
  __shared__ __attribute__((aligned(16))) short Bs[128*32];
  const int tid = threadIdx.x;
  const int w = tid>>6, l = tid&63;
  const int m0 = blockIdx.x*128;
  const int n0 = blockIdx.y*128;
  const int quad = l>>4, lm = l&15;
  const int wm = (w&1)*64, wn = (w>>1)*64;

  f32x4 acc[4][4];
  #pragma unroll
  for (int i=0;i<4;i++)
    #pragma unroll
    for (int j=0;j<4;j++){ f32x4 z = {0.f,0.f,0.f,0.f}; acc[i][j] = z; }

  const int cA = w*64 + l;                 // 16B chunk id; row = c>>2, sub = c&3
  const char* Ab = (const char*)(A  + (size_t)m0*FDIM) + (size_t)(cA>>2)*1024 + (cA&3)*16;
  const char* Bb = (const char*)(BT + (size_t)n0*FDIM) + (size_t)(cA>>2)*1024 + (cA&3)*16;
  char* ldsA = (char*)As + w*1024;         // wave-uniform LDS base; HW adds lane*16
  char* ldsB = (char*)Bs + w*1024;

  for (int kb=0; kb<512; kb+=32){
    __syncthreads();
    async16(Ab + kb*2,         ldsA);
    async16(Ab + kb*2 + 65536, ldsA + 4096);
    async16(Bb + kb*2,         ldsB);
    async16(Bb + kb*2 + 65536, ldsB + 4096);
    __syncthreads();
    frag8 af[4], bfrg[4];
    #pragma unroll
    for (int i=0;i<4;i++) af[i]   = *(const frag8*)(As + (wm+i*16+lm)*32 + quad*8);
    #pragma unroll
    for (int j=0;j<4;j++) bfrg[j] = *(const frag8*)(Bs + (wn+j*16+lm)*32 + quad*8);
    #pragma unroll
    for (int i=0;i<4;i++)
      #pragma unroll
      for (int j=0;j<4;j++)
        acc[i][j] = __builtin_amdgcn_mfma_f32_16x16x32_bf16(af[i], bfrg[j], acc[i][j], 0,0,0);
  }

  float bias[4]; int cols[4];
  #pragma unroll
  for (int j=0;j<4;j++){
    const int c = n0 + wn + j*16 + lm;
    cols[j] = c;
    if (MODE==0) bias[j] = (c<512 ? b0[c] : (c<1024 ? b1[c-512] : b2[c-1024]));
    else         bias[j] = b0[c];
  }
  #pragma unroll
  for (int i=0;i<4;i++){
    const int rbase = m0 + wm + i*16 + quad*4;
    #pragma unroll
    for (int r=0;r<4;r++){
      const size_t row = (size_t)(rbase + r);
      #pragma unroll
      for (int j=0;j<4;j++){
        float v = acc[i][j][r] + bias[j];
        if (MODE==1) v += bf1(resid[row*FDIM + cols[j]]);
        C[row*(size_t)ldC + cols[j]] = f2bf(v);
      }
    }
  }
}

// -------------------- per-token head-attention + residual(bf16) + LN1 (1 wave = 1 token) --------------------
__global__ __launch_bounds__(256) void attn_ln1(const u16* __restrict__ qkvb,
    const u16* __restrict__ xb, const float* __restrict__ gam, const float* __restrict__ bet,
    u16* __restrict__ y1b){
  __shared__ __attribute__((aligned(16))) u16 sQ[4][1536];
  __shared__ float sWt[4][64];
  const int tid = threadIdx.x, w = tid>>6, l = tid&63;
  const int t = blockIdx.x*4 + w;
  {
    const int4* src = (const int4*)(qkvb + (size_t)t*1536);
    int4* dst = (int4*)(&sQ[w][0]);
    #pragma unroll
    for (int i=0;i<3;i++) dst[i*64 + l] = src[i*64 + l];
  }
  __syncthreads();
  const int h = l>>3, g = l&7;
  const u16* qrow = &sQ[w][h*64];
  const u16* krow = &sQ[w][512 + g*64];
  float sc = 0.f;
  const int dstart = (l&31)*2;
  #pragma unroll
  for (int i=0;i<32;i++){
    const int d = (dstart + 2*i) & 63;
    const uint32_t qp = *(const uint32_t*)(qrow + d);
    const uint32_t kp = *(const uint32_t*)(krow + d);
    sc += bflo(qp)*bflo(kp) + bfhi(qp)*bfhi(kp);
  }
  float mx = sc;
  mx = fmaxf(mx, __shfl_xor(mx,1));
  mx = fmaxf(mx, __shfl_xor(mx,2));
  mx = fmaxf(mx, __shfl_xor(mx,4));
  const float e = __expf(sc - mx);
  float ssum = e;
  ssum += __shfl_xor(ssum,1);
  ssum += __shfl_xor(ssum,2);
  ssum += __shfl_xor(ssum,4);
  sWt[w][l] = e / ssum;
  __syncthreads();
  float wt[8];
  #pragma unroll
  for (int gg=0;gg<8;gg++) wt[gg] = sWt[w][h*8+gg];
  float att[8] = {0,0,0,0,0,0,0,0};
  const int d0 = (l&7)*8;
  #pragma unroll
  for (int gg=0;gg<8;gg++){
    const int4 vv = *(const int4*)(&sQ[w][1024 + gg*64 + d0]);
    const uint32_t* vp = (const uint32_t*)&vv;
    #pragma unroll
    for (int p=0;p<4;p++){
      att[2*p]   += wt[gg]*bflo(vp[p]);
      att[2*p+1] += wt[gg]*bfhi(vp[p]);
    }
  }
  const size_t rb = (size_t)t*FDIM + l*8;
  const int4 xv = *(const int4*)(xb + rb);
  const uint32_t* xp = (const uint32_t*)&xv;
  float y[8]; float s1=0.f, s2=0.f;
  #pragma unroll
  for (int p=0;p<4;p++){
    y[2*p]   = att[2*p]   + bflo(xp[p]);
    y[2*p+1] = att[2*p+1] + bfhi(xp[p]);
  }
  #pragma unroll
  for (int j=0;j<8;j++){ s1 += y[j]; s2 += y[j]*y[j]; }
  #pragma unroll
  for (int off=1; off<64; off<<=1){ s1 += __shfl_xor(s1,off); s2 += __shfl_xor(s2,off); }
  const float mean = s1*(1.f/512.f);
  const float var  = s2*(1.f/512.f) - mean*mean;
  const float rstd = rsqrtf(var + 1e-5f);
  const float4 g0 = *(const float4*)(gam + l*8);
  const float4 g1v = *(const float4*)(gam + l*8 + 4);
  const float4 b0v = *(const float4*)(bet + l*8);
  const float4 b1v = *(const float4*)(bet + l*8 + 4);
  float of[8];
  of[0]=(y[0]-mean)*rstd*g0.x + b0v.x;
  of[1]=(y[1]-mean)*rstd*g0.y + b0v.y;
  of[2]=(y[2]-mean)*rstd*g0.z + b0v.z;
  of[3]=(y[3]-mean)*rstd*g0.w + b0v.w;
  of[4]=(y[4]-mean)*rstd*g1v.x + b1v.x;
  of[5]=(y[5]-mean)*rstd*g1v.y + b1v.y;
  of[6]=(y[6]-mean)*rstd*g1v.z + b1v.z;
  of[7]=(y[7]-mean)*rstd*g1v.w + b1v.w;
  u16 ob[8] __attribute__((aligned(16)));
  #pragma unroll
  for (int j=0;j<8;j++) ob[j] = f2bf(of[j]);
  *(int4*)(y1b + rb) = *(const int4*)ob;
}

// -------------------- LN2 over z (bf16); writes bf16 xb (next layer) or fp32 out --------------------
__global__ __launch_bounds__(256) void ln2_kernel(const u16* __restrict__ z,
    const float* __restrict__ gam, const float* __restrict__ bet,
    u16* __restrict__ xb, float* __restrict__ outp, const int final_){
  const int tid = threadIdx.x, w = tid>>6, l = tid&63;
  const int t = blockIdx.x*4 + w;
  const size_t rb = (size_t)t*FDIM + l*8;
  const int4 zv = *(const int4*)(z + rb);
  const uint32_t* zp = (const uint32_t*)&zv;
  float y[8];
  #pragma unroll
  for (int p=0;p<4;p++){ y[2*p]=bflo(zp[p]); y[2*p+1]=bfhi(zp[p]); }
  float s1=0.f, s2=0.f;
  #pragma unroll
  for (int j=0;j<8;j++){ s1+=y[j]; s2+=y[j]*y[j]; }
  #pragma unroll
  for (int off=1; off<64; off<<=1){ s1 += __shfl_xor(s1,off); s2 += __shfl_xor(s2,off); }
  const float mean = s1*(1.f/512.f);
  const float var  = s2*(1.f/512.f) - mean*mean;
  const float rstd = rsqrtf(var + 1e-5f);
  const float4 g0 = *(const float4*)(gam + l*8);
  const float4 g1v = *(const float4*)(gam + l*8 + 4);
  const float4 b0v = *(const float4*)(bet + l*8);
  const float4 b1v = *(const float4*)(bet + l*8 + 4);
  float of[8];
  of[0]=(y[0]-mean)*rstd*g0.x + b0v.x;
  of[1]=(y[1]-mean)*rstd*g0.y + b0v.y;
  of[2]=(y[2]-mean)*rstd*g0.z + b0v.z;
  of[3]=(y[3]-mean)*rstd*g0.w + b0v.w;
  of[4]=(y[4]-mean)*rstd*g1v.x + b1v.x;
  of[5]=(y[5]-mean)*rstd*g1v.y + b1v.y;
  of[6]=(y[6]-mean)*rstd*g1v.z + b1v.z;
  of[7]=(y[7]-mean)*rstd*g1v.w + b1v.w;
  if (final_){
    float4 o0; o0.x=of[0]; o0.y=of[1]; o0.z=of[2]; o0.w=of[3];
    float4 o1; o1.x=of[4]; o1.y=of[5]; o1.z=of[6]; o1.w=of[7];
    *(float4*)(outp + rb) = o0;
    *(float4*)(outp + rb + 4) = o1;
  } else {
    u16 ob[8] __attribute__((aligned(16)));
    #pragma unroll
    for (int j=0;j<8;j++) ob[j] = f2bf(of[j]);
    *(int4*)(xb + rb) = *(const int4*)ob;
  }
}

extern "C" void kernel_launch(void* const* d_in, const int* in_sizes, int n_in,
                              void* d_out, int out_size, void* d_ws, size_t ws_size,
                              hipStream_t stream){
  const int*   text = (const int*)d_in[0];
  const float* emb = (const float*)d_in[1];
  const float* pe  = (const float*)d_in[2];
  const float* Wq  = (const float*)d_in[3];
  const float* bq  = (const float*)d_in[4];
  const float* Wk  = (const float*)d_in[5];
  const float* bk  = (const float*)d_in[6];
  const float* Wv  = (const float*)d_in[7];
  const float* bv  = (const float*)d_in[8];
  const float* g1  = (const float*)d_in[9];
  const float* be1 = (const float*)d_in[10];
  const float* Wf  = (const float*)d_in[11];
  const float* bf_ = (const float*)d_in[12];
  const float* g2  = (const float*)d_in[13];
  const float* be2 = (const float*)d_in[14];
  float* outp = (float*)d_out;               // reference output dtype = float32

  // ---- layout: WT 12.6 MB + per-token {xb 1024 + y1b 1024 + qkv 3072} = 5120 B
  const size_t wtB = (size_t)6*2048*512*2;
  int T = NTOK;                               // single chunk if ws permits (needs ~173 MB; R7 confirmed)
  while (T > 2048 && wtB + (size_t)T*5120 > ws_size) T >>= 1;

  char* ws = (char*)d_ws;
  u16*   WT  = (u16*)ws;
  char*  act = ws + wtB;
  u16*   xb  = (u16*)act;                       // T*1024 B
  u16*   y1b = (u16*)(act + (size_t)T*1024);    // T*1024 B
  u16*   qkv = (u16*)(act + (size_t)T*2048);    // T*3072 B
  u16*   zb  = qkv;                             // alias: qkv dead once attn_ln1 ran

  hipLaunchKernelGGL(transpose_w, dim3(3072), dim3(256), 0, stream, Wq, Wk, Wv, Wf, WT);

  const int chunks = NTOK / T;
  for (int c = 0; c < chunks; c++){
    const int tok0 = c*T;
    hipLaunchKernelGGL(embed_kernel, dim3(T/2), dim3(256), 0, stream, text, emb, pe, xb, tok0);
    for (int lay=0; lay<6; lay++){
      const u16* WTl = WT + (size_t)lay*2048*FDIM;
      hipLaunchKernelGGL((gemm_mfma<0>), dim3(T/128, 12), dim3(256), 0, stream,
          xb, WTl, bq + lay*FDIM, bk + lay*FDIM, bv + lay*FDIM, (const u16*)nullptr, qkv, 1536);
      hipLaunchKernelGGL(attn_ln1, dim3(T/4), dim3(256), 0, stream,
          qkv, xb, g1 + lay*FDIM, be1 + lay*FDIM, y1b);
      hipLaunchKernelGGL((gemm_mfma<1>), dim3(T/128, 4), dim3(256), 0, stream,
          y1b, WTl + (size_t)1536*FDIM, bf_ + lay*FDIM, (const float*)nullptr, (const float*)nullptr,
          y1b, zb, 512);
      hipLaunchKernelGGL(ln2_kernel, dim3(T/4), dim3(256), 0, stream,
          zb, g2 + lay*FDIM, be2 + lay*FDIM, xb, outp + (size_t)tok0*FDIM, (lay==5)?1:0);
    }
  }
}